// Round 10
// baseline (1392.626 us; speedup 1.0000x reference)
//
#include <hip/hip_runtime.h>

#define B_ 64
#define T_ 2048
#define I_ 128
#define H_ 128
#define CHUNK 128
#define NCHUNK (T_ / CHUNK)

typedef float f32x4 __attribute__((ext_vector_type(4)));
typedef int   i32x4 __attribute__((ext_vector_type(4)));

// ---------------- Phase 1: xp = x @ W_xh^T + (b_xh + b_hh) ----------------
__global__ __launch_bounds__(256) void xp_gemm(
    const float* __restrict__ x, const float* __restrict__ Wxh,
    const float* __restrict__ bxh, const float* __restrict__ bhh,
    float* __restrict__ xp)
{
    __shared__ float ws[H_ * I_];   // 64 KB, row-major [h][i]
    const int tid = threadIdx.x;
    {
        const float4* src = (const float4*)Wxh;
        float4* dst = (float4*)ws;
        #pragma unroll
        for (int i = 0; i < (H_ * I_ / 4) / 256; ++i)
            dst[tid + i * 256] = src[tid + i * 256];
    }
    __syncthreads();

    const int r0 = (tid >> 4) * 8;
    const int c0 = (tid & 15) * 8;
    const float* xb = x + ((size_t)blockIdx.x * 128 + r0) * I_;
    const float* wb = ws + c0 * I_;

    float acc[8][8];
    #pragma unroll
    for (int i = 0; i < 8; ++i)
        #pragma unroll
        for (int j = 0; j < 8; ++j) acc[i][j] = 0.f;

    float4 xa[8], wa[8], xn[8], wn[8];
    #pragma unroll
    for (int i = 0; i < 8; ++i) xa[i] = *(const float4*)(xb + i * I_);
    #pragma unroll
    for (int j = 0; j < 8; ++j) wa[j] = *(const float4*)(wb + j * I_);

    for (int k4 = 0; k4 < 32; k4 += 2) {
        #pragma unroll
        for (int i = 0; i < 8; ++i) xn[i] = *(const float4*)(xb + i * I_ + k4 * 4 + 4);
        #pragma unroll
        for (int j = 0; j < 8; ++j) wn[j] = *(const float4*)(wb + j * I_ + k4 * 4 + 4);
        #pragma unroll
        for (int i = 0; i < 8; ++i)
            #pragma unroll
            for (int j = 0; j < 8; ++j) {
                acc[i][j] = fmaf(xa[i].x, wa[j].x, acc[i][j]);
                acc[i][j] = fmaf(xa[i].y, wa[j].y, acc[i][j]);
                acc[i][j] = fmaf(xa[i].z, wa[j].z, acc[i][j]);
                acc[i][j] = fmaf(xa[i].w, wa[j].w, acc[i][j]);
            }
        if (k4 + 2 < 32) {
            #pragma unroll
            for (int i = 0; i < 8; ++i) xa[i] = *(const float4*)(xb + i * I_ + k4 * 4 + 8);
            #pragma unroll
            for (int j = 0; j < 8; ++j) wa[j] = *(const float4*)(wb + j * I_ + k4 * 4 + 8);
        }
        #pragma unroll
        for (int i = 0; i < 8; ++i)
            #pragma unroll
            for (int j = 0; j < 8; ++j) {
                acc[i][j] = fmaf(xn[i].x, wn[j].x, acc[i][j]);
                acc[i][j] = fmaf(xn[i].y, wn[j].y, acc[i][j]);
                acc[i][j] = fmaf(xn[i].z, wn[j].z, acc[i][j]);
                acc[i][j] = fmaf(xn[i].w, wn[j].w, acc[i][j]);
            }
    }

    const float4 ba0 = *(const float4*)(bxh + c0);
    const float4 ba1 = *(const float4*)(bxh + c0 + 4);
    const float4 bb0 = *(const float4*)(bhh + c0);
    const float4 bb1 = *(const float4*)(bhh + c0 + 4);
    float* orow = xp + ((size_t)blockIdx.x * 128 + r0) * H_ + c0;
    #pragma unroll
    for (int i = 0; i < 8; ++i) {
        float4 o0, o1;
        o0.x = acc[i][0] + ba0.x + bb0.x; o0.y = acc[i][1] + ba0.y + bb0.y;
        o0.z = acc[i][2] + ba0.z + bb0.z; o0.w = acc[i][3] + ba0.w + bb0.w;
        o1.x = acc[i][4] + ba1.x + bb1.x; o1.y = acc[i][5] + ba1.y + bb1.y;
        o1.z = acc[i][6] + ba1.z + bb1.z; o1.w = acc[i][7] + ba1.w + bb1.w;
        *(float4*)(orow + i * H_) = o0;
        *(float4*)(orow + i * H_ + 4) = o1;
    }
}

// Stage one 128-step xp chunk (64 KB) into LDS, 64 lanes x 16 B x 64 iters.
__device__ __forceinline__ void stage_chunk64(const float* __restrict__ g,
                                              float* l, int ln)
{
    #pragma unroll
    for (int i = 0; i < 64; ++i) {
        const int off = i * 256;
        __builtin_amdgcn_global_load_lds(
            (const __attribute__((address_space(1))) unsigned int*)(g + off + ln * 4),
            (__attribute__((address_space(3))) unsigned int*)(l + off),
            16, 0, 0);
    }
}

// ---------------- Phase 2: scan, ONE WAVE per batch, lane-local recurrence ----
// y = W_hh @ h via D = A*B + C with A = W (static, AGPR), B = h (replicated
// across the 16 cols), C = xp fragment. Layouts (16x16x32_f16):
//   A: lane(g,c15) holds A[row=c15][k=8g+e]          (std; B-version R9-verified)
//   D: lane holds rows 16m+4g+r, col c15 (m89-verified) -> y[16m+4g+r]
// Owner pair P = 8*(c15>>1)+2g+(c15&1): lane tanhs y[2P],y[2P+1], packs f16,
// writes ONE dword to hx; next step's B_q = hx dwords [16g+4q..+3] -- the
// permutation works out so B is exactly 4 ds_read_b128 broadcasts. No other
// cross-lane traffic, no barriers; xp enters as MFMA C-operand.
__global__ __launch_bounds__(64) void rnn_scan(
    const float* __restrict__ Whh,
    float* __restrict__ seq /* xp in, h_seq out */, float* __restrict__ hlast)
{
    __shared__ float xpl[2][CHUNK * H_];   // 128 KB
    __shared__ unsigned hx[64];            // packed-f16 h exchange, 256 B

    const int l   = threadIdx.x;           // 0..63
    const int b   = blockIdx.x;
    const int c15 = l & 15;
    const int gp  = l >> 4;
    const bool s1 = (c15 & 1);

    // ---- W fragments: A[m][q], f16-packed, pinned in AGPRs ----
    i32x4 wA[8][4];
    #pragma unroll
    for (int m = 0; m < 8; ++m) {
        const float* wr = Whh + (size_t)(16 * m + c15) * H_;
        #pragma unroll
        for (int q = 0; q < 4; ++q) {
            const float4 u0 = *(const float4*)(wr + 32 * q + 8 * gp);
            const float4 u1 = *(const float4*)(wr + 32 * q + 8 * gp + 4);
            i32x4 t;
            t.x = __builtin_bit_cast(int, __builtin_amdgcn_cvt_pkrtz(u0.x, u0.y));
            t.y = __builtin_bit_cast(int, __builtin_amdgcn_cvt_pkrtz(u0.z, u0.w));
            t.z = __builtin_bit_cast(int, __builtin_amdgcn_cvt_pkrtz(u1.x, u1.y));
            t.w = __builtin_bit_cast(int, __builtin_amdgcn_cvt_pkrtz(u1.z, u1.w));
            wA[m][q] = t;
            asm("" : "+a"(wA[m][q]));      // force AGPR residency, no remat
        }
    }

    const int P     = 8 * (c15 >> 1) + 2 * gp + (c15 & 1);
    const int Lw    = 16 * ((P >> 2) & 3) + 4 * (P >> 4) + (P & 3);
    const int stoff = 2 * P;

    hx[l] = 0u;                             // h0 = 0
    asm volatile("" ::: "memory");
    const i32x4* hxv = (const i32x4*)hx;
    i32x4 Bv0 = hxv[4 * gp + 0], Bv1 = hxv[4 * gp + 1],
          Bv2 = hxv[4 * gp + 2], Bv3 = hxv[4 * gp + 3];

    float* xp = seq + (size_t)b * T_ * H_;
    stage_chunk64(xp, &xpl[0][0], l);       // prologue: chunk 0

    f32x4 xa[8];
    float h0v = 0.f, h1v = 0.f;

    for (int c = 0; c < NCHUNK; ++c) {
        asm volatile("s_waitcnt vmcnt(0)" ::: "memory");   // chunk-c LDS ready
        if (c + 1 < NCHUNK)
            stage_chunk64(xp + (size_t)(c + 1) * CHUNK * H_, &xpl[(c + 1) & 1][0], l);

        const float* xb = &xpl[c & 1][0];
        float* sq = xp + (size_t)c * CHUNK * H_;
        #pragma unroll
        for (int m = 0; m < 8; ++m)          // C-in for t=0 of this chunk
            xa[m] = *(const f32x4*)(xb + 16 * m + 4 * gp);

        for (int t = 0; t < CHUNK; ++t) {
            // ---- 32 MFMA: xa[m] = xp_frag + W h  (A from AGPR, zero copies) ----
            #pragma unroll
            for (int m = 0; m < 8; ++m) {
                asm("v_mfma_f32_16x16x32_f16 %0, %1, %2, %0" : "+v"(xa[m]) : "a"(wA[m][0]), "v"(Bv0));
                asm("v_mfma_f32_16x16x32_f16 %0, %1, %2, %0" : "+v"(xa[m]) : "a"(wA[m][1]), "v"(Bv1));
                asm("v_mfma_f32_16x16x32_f16 %0, %1, %2, %0" : "+v"(xa[m]) : "a"(wA[m][2]), "v"(Bv2));
                asm("v_mfma_f32_16x16x32_f16 %0, %1, %2, %0" : "+v"(xa[m]) : "a"(wA[m][3]), "v"(Bv3));
            }
            // ---- select my owned pair (static cndmask tree on c15) ----
            float e0[8], e1[8];
            #pragma unroll
            for (int m = 0; m < 8; ++m) {
                e0[m] = s1 ? xa[m].z : xa[m].x;
                e1[m] = s1 ? xa[m].w : xa[m].y;
            }
            float f0[4], f1[4];
            #pragma unroll
            for (int i = 0; i < 4; ++i) {
                f0[i] = (c15 & 2) ? e0[2 * i + 1] : e0[2 * i];
                f1[i] = (c15 & 2) ? e1[2 * i + 1] : e1[2 * i];
            }
            const float p0 = (c15 & 8) ? ((c15 & 4) ? f0[3] : f0[2])
                                       : ((c15 & 4) ? f0[1] : f0[0]);
            const float p1 = (c15 & 8) ? ((c15 & 4) ? f1[3] : f1[2])
                                       : ((c15 & 4) ? f1[1] : f1[0]);
            // ---- prefetch next step's xp frags (overwrites consumed acc) ----
            const float* nx = xb + (size_t)((t + 1 < CHUNK) ? t + 1 : t) * H_;
            #pragma unroll
            for (int m = 0; m < 8; ++m)
                xa[m] = *(const f32x4*)(nx + 16 * m + 4 * gp);
            // ---- tanh of the 2 owned values ----
            const float q0 = exp2f(p0 * 2.8853900817779268f);
            const float q1 = exp2f(p1 * 2.8853900817779268f);
            h0v = 1.f - 2.f * __builtin_amdgcn_rcpf(q0 + 1.f);
            h1v = 1.f - 2.f * __builtin_amdgcn_rcpf(q1 + 1.f);
            // ---- publish h pair; read next B (same-wave DS pipe is in-order) ----
            hx[Lw] = __builtin_bit_cast(unsigned, __builtin_amdgcn_cvt_pkrtz(h0v, h1v));
            asm volatile("" ::: "memory");
            Bv0 = hxv[4 * gp + 0]; Bv1 = hxv[4 * gp + 1];
            Bv2 = hxv[4 * gp + 2]; Bv3 = hxv[4 * gp + 3];
            // ---- h_seq store (queued, off the critical path) ----
            *(float2*)(sq + (size_t)t * H_ + stoff) = make_float2(h0v, h1v);
        }
    }
    *(float2*)&hlast[b * H_ + stoff] = make_float2(h0v, h1v);
}

extern "C" void kernel_launch(void* const* d_in, const int* in_sizes, int n_in,
                              void* d_out, int out_size, void* d_ws, size_t ws_size,
                              hipStream_t stream)
{
    const float* x   = (const float*)d_in[0];
    const float* Wxh = (const float*)d_in[1];
    const float* bxh = (const float*)d_in[2];
    const float* Whh = (const float*)d_in[3];
    const float* bhh = (const float*)d_in[4];
    float* out   = (float*)d_out;
    float* hlast = out + (size_t)B_ * T_ * H_;

    xp_gemm<<<(B_ * T_) / 128, 256, 0, stream>>>(x, Wxh, bxh, bhh, out);
    rnn_scan<<<B_, 64, 0, stream>>>(Whh, out, hlast);
}